// Round 1
// baseline (9202.483 us; speedup 1.0000x reference)
//
#include <hip/hip_runtime.h>
#include <cfloat>
#include <cmath>
#include <cstdint>

#define DD 768
#define MM 256
#define NKB 200000
#define SLEN 512
#define KK 200      // 2*top_k
#define TOPK 100
#define NBINS 2048
#define CAP 1024

// ---------------- Kernel A: mention embeddings (masked mean, f64) ----------------
__global__ __launch_bounds__(256) void k_mention_emb(
    const float* __restrict__ text, const int* __restrict__ msent,
    const int* __restrict__ mstart, const int* __restrict__ mlen,
    double* __restrict__ me64) {
  int m = blockIdx.x;
  int sent = msent[m], st = mstart[m], ln = mlen[m];
  const float* base = text + (size_t)sent * SLEN * DD;
  for (int d = threadIdx.x; d < DD; d += blockDim.x) {
    double acc = 0.0;
    for (int s = st; s <= st + ln; ++s) acc += (double)base[(size_t)s * DD + d];
    me64[(size_t)m * DD + d] = acc / (double)(ln + 1);
  }
}

// ---------------- Kernel B1: query = me @ W_ret^T + b_ret (f64) ----------------
__global__ __launch_bounds__(256) void k_query(
    const double* __restrict__ me64, const float* __restrict__ Wret,
    const float* __restrict__ bret, double* __restrict__ q64, float* __restrict__ q32) {
  int m = blockIdx.x;
  __shared__ double sme[DD];
  for (int d = threadIdx.x; d < DD; d += blockDim.x) sme[d] = me64[(size_t)m * DD + d];
  __syncthreads();
  for (int e = threadIdx.x; e < DD; e += blockDim.x) {
    double acc = (double)bret[e];
    const float* wr = Wret + (size_t)e * DD;
    for (int d = 0; d < DD; ++d) acc += sme[d] * (double)wr[d];
    q64[(size_t)m * DD + e] = acc;
    q32[(size_t)m * DD + e] = (float)acc;
  }
}

// ---------------- Kernel B2: m_part = me @ Ws1[:D] (f64) ----------------
__global__ __launch_bounds__(256) void k_mpart(
    const double* __restrict__ me64, const float* __restrict__ Ws1,
    double* __restrict__ mp64) {
  int m = blockIdx.x;
  __shared__ double sme[DD];
  for (int d = threadIdx.x; d < DD; d += blockDim.x) sme[d] = me64[(size_t)m * DD + d];
  __syncthreads();
  for (int e = threadIdx.x; e < DD; e += blockDim.x) {
    double acc = 0.0;
    for (int d = 0; d < DD; ++d) acc += sme[d] * (double)Ws1[(size_t)d * DD + e];
    mp64[(size_t)m * DD + e] = acc;
  }
}

// ---------------- Kernel C: sims = q32 @ kb^T (f32 SGEMM, 64x64 tile) ----------------
__global__ __launch_bounds__(256) void k_sims(
    const float* __restrict__ q32, const float* __restrict__ kb,
    float* __restrict__ sims, int mbase, int mcount) {
  __shared__ float As[32][68];
  __shared__ float Bs[32][68];
  int bn = blockIdx.x;            // 0..3124
  int bm = blockIdx.y;
  int tid = threadIdx.x;
  int tx = tid & 15, ty = tid >> 4;
  const int n0 = bn * 64;
  const int m0 = bm * 64;
  float acc[4][4] = {};
  for (int k0 = 0; k0 < DD; k0 += 32) {
    for (int i = tid; i < 64 * 32; i += 256) {
      int k = i & 31, mm = i >> 5;
      int gm = m0 + mm; if (gm >= mcount) gm = 0;
      As[k][mm] = q32[(size_t)(mbase + gm) * DD + k0 + k];
    }
    for (int i = tid; i < 64 * 32; i += 256) {
      int k = i & 31, nn = i >> 5;
      Bs[k][nn] = kb[(size_t)(n0 + nn) * DD + k0 + k];
    }
    __syncthreads();
#pragma unroll
    for (int k = 0; k < 32; ++k) {
      float4 a = *(const float4*)&As[k][ty * 4];
      float4 b = *(const float4*)&Bs[k][tx * 4];
      acc[0][0] += a.x * b.x; acc[0][1] += a.x * b.y; acc[0][2] += a.x * b.z; acc[0][3] += a.x * b.w;
      acc[1][0] += a.y * b.x; acc[1][1] += a.y * b.y; acc[1][2] += a.y * b.z; acc[1][3] += a.y * b.w;
      acc[2][0] += a.z * b.x; acc[2][1] += a.z * b.y; acc[2][2] += a.z * b.z; acc[2][3] += a.z * b.w;
      acc[3][0] += a.w * b.x; acc[3][1] += a.w * b.y; acc[3][2] += a.w * b.z; acc[3][3] += a.w * b.w;
    }
    __syncthreads();
  }
  for (int i = 0; i < 4; ++i) {
    int gm = m0 + ty * 4 + i;
    if (gm < mcount) {
      float4 v = make_float4(acc[i][0], acc[i][1], acc[i][2], acc[i][3]);
      *(float4*)&sims[(size_t)gm * NKB + n0 + tx * 4] = v;
    }
  }
}

// ------- Kernel D: per-mention top-200 (histogram select + f64 rescore + bitonic) -------
__global__ __launch_bounds__(256) void k_topk(
    const float* __restrict__ sims, const float* __restrict__ kb,
    const double* __restrict__ q64, int mbase, int* __restrict__ cidx) {
  int lm = blockIdx.x;
  int m = mbase + lm;
  const float* row = sims + (size_t)lm * NKB;
  __shared__ float sred[256];
  __shared__ int   hist[NBINS];
  __shared__ int   sbidx[CAP];
  __shared__ double skey[CAP];
  __shared__ double sq[DD];
  __shared__ float sminmax[2];
  __shared__ int   scnt, sbsel;
  int tid = threadIdx.x;

  for (int d = tid; d < DD; d += 256) sq[d] = q64[(size_t)m * DD + d];

  // phase 1: min/max
  float vmin = FLT_MAX, vmax = -FLT_MAX;
  for (int i = tid; i < NKB; i += 256) {
    float v = row[i];
    vmin = fminf(vmin, v); vmax = fmaxf(vmax, v);
  }
  sred[tid] = vmax; __syncthreads();
  for (int s = 128; s > 0; s >>= 1) { if (tid < s) sred[tid] = fmaxf(sred[tid], sred[tid + s]); __syncthreads(); }
  if (tid == 0) sminmax[1] = sred[0];
  __syncthreads();
  sred[tid] = vmin; __syncthreads();
  for (int s = 128; s > 0; s >>= 1) { if (tid < s) sred[tid] = fminf(sred[tid], sred[tid + s]); __syncthreads(); }
  if (tid == 0) sminmax[0] = sred[0];
  for (int i = tid; i < NBINS; i += 256) hist[i] = 0;
  __syncthreads();
  float fmin = sminmax[0], fmax = sminmax[1];
  float scale = (fmax > fmin) ? (float)NBINS / (fmax - fmin) : 0.f;

  // phase 2: histogram
  for (int i = tid; i < NKB; i += 256) {
    int b = (int)((row[i] - fmin) * scale);
    b = b < 0 ? 0 : (b > NBINS - 1 ? NBINS - 1 : b);
    atomicAdd(&hist[b], 1);
  }
  __syncthreads();

  // phase 3: find boundary bin (suffix count >= KK), margin 1 bin
  if (tid == 0) {
    int cum = 0, b = NBINS - 1;
    for (; b >= 0; --b) { cum += hist[b]; if (cum >= KK) break; }
    if (b < 0) b = 0;
    sbsel = (b > 0) ? b - 1 : 0;
    scnt = 0;
  }
  __syncthreads();
  int bsel = sbsel;

  // phase 4: compact candidate indices
  for (int i = tid; i < NKB; i += 256) {
    float v = row[i];
    int b = (int)((v - fmin) * scale);
    b = b < 0 ? 0 : (b > NBINS - 1 ? NBINS - 1 : b);
    if (b >= bsel) {
      int p = atomicAdd(&scnt, 1);
      if (p < CAP) sbidx[p] = i;
    }
  }
  __syncthreads();
  int cnt = scnt; if (cnt > CAP) cnt = CAP;

  // phase 5: exact f64 rescore (one wave per candidate)
  int lane = tid & 63, wid = tid >> 6;
  for (int c = wid; c < cnt; c += 4) {
    const float* krow = kb + (size_t)sbidx[c] * DD;
    double s = 0.0;
    for (int d = lane; d < DD; d += 64) s += sq[d] * (double)krow[d];
    for (int off = 32; off > 0; off >>= 1) s += __shfl_down(s, off, 64);
    if (lane == 0) skey[c] = s;
  }
  for (int c = cnt + tid; c < CAP; c += 256) { skey[c] = -INFINITY; sbidx[c] = 0x7fffffff; }
  __syncthreads();

  // phase 6: bitonic sort CAP elems, desc by key, tie -> smaller idx first
  for (int k = 2; k <= CAP; k <<= 1) {
    for (int j = k >> 1; j > 0; j >>= 1) {
      for (int i = tid; i < CAP; i += 256) {
        int l = i ^ j;
        if (l > i) {
          double ka = skey[i], kb2 = skey[l];
          int ia = sbidx[i], ib = sbidx[l];
          bool lBefore = (kb2 > ka) || (kb2 == ka && ib < ia);
          bool iBefore = (ka > kb2) || (ka == kb2 && ia < ib);
          bool dir = ((i & k) == 0);
          bool sw = dir ? lBefore : iBefore;
          if (sw) { skey[i] = kb2; skey[l] = ka; sbidx[i] = ib; sbidx[l] = ia; }
        }
      }
      __syncthreads();
    }
  }
  for (int c = tid; c < KK; c += 256) cidx[(size_t)m * KK + c] = sbidx[c];
}

// ------- Kernel E: scorer — z = sum_e relu(mp + cand@Ws1[D:] + bs1)*Ws2 + bs2 (f64 acc) -------
#define TM 16
__global__ __launch_bounds__(256) void k_score(
    const float* __restrict__ kb, const int* __restrict__ cidx,
    const double* __restrict__ mp64, const float* __restrict__ Ws1,
    const float* __restrict__ bs1, const float* __restrict__ Ws2,
    const float* __restrict__ bs2, double* __restrict__ z64) {
  __shared__ float As[TM][DD];       // 48 KB
  __shared__ float Bs[32][68];       // 8.5 KB
  __shared__ int srow[TM];
  __shared__ int smen[TM];
  int r0 = blockIdx.x * TM;
  int tid = threadIdx.x;
  if (tid < TM) {
    int r = r0 + tid;
    srow[tid] = cidx[r];
    smen[tid] = r / KK;
  }
  __syncthreads();
  for (int rr = 0; rr < TM; ++rr) {
    const float* krow = kb + (size_t)srow[rr] * DD;
    for (int d = tid; d < DD; d += 256) As[rr][d] = krow[d];
  }
  __syncthreads();
  int tx = tid & 15, ty = tid >> 4;
  int m = smen[ty];
  double pz = 0.0;
  for (int e0 = 0; e0 < DD; e0 += 64) {
    double acc0 = 0, acc1 = 0, acc2 = 0, acc3 = 0;
    for (int k0 = 0; k0 < DD; k0 += 32) {
      for (int i = tid; i < 32 * 64; i += 256) {
        int kk = i >> 6, ee = i & 63;
        Bs[kk][ee] = Ws1[(size_t)(DD + k0 + kk) * DD + e0 + ee];
      }
      __syncthreads();
#pragma unroll
      for (int kk = 0; kk < 32; ++kk) {
        double a = (double)As[ty][k0 + kk];
        float4 b = *(const float4*)&Bs[kk][tx * 4];
        acc0 += a * (double)b.x;
        acc1 += a * (double)b.y;
        acc2 += a * (double)b.z;
        acc3 += a * (double)b.w;
      }
      __syncthreads();
    }
    int eb = e0 + tx * 4;
    double h;
    h = mp64[(size_t)m * DD + eb + 0] + acc0 + (double)bs1[eb + 0]; if (h > 0) pz += h * (double)Ws2[eb + 0];
    h = mp64[(size_t)m * DD + eb + 1] + acc1 + (double)bs1[eb + 1]; if (h > 0) pz += h * (double)Ws2[eb + 1];
    h = mp64[(size_t)m * DD + eb + 2] + acc2 + (double)bs1[eb + 2]; if (h > 0) pz += h * (double)Ws2[eb + 2];
    h = mp64[(size_t)m * DD + eb + 3] + acc3 + (double)bs1[eb + 3]; if (h > 0) pz += h * (double)Ws2[eb + 3];
  }
  for (int off = 1; off < 16; off <<= 1) pz += __shfl_xor(pz, off, 64);
  if (tx == 0) z64[r0 + ty] = pz + (double)bs2[0];
}

// ---------------- Kernel F: per-mention top-100 of 200 (bitonic 256) ----------------
__global__ __launch_bounds__(256) void k_final(
    const double* __restrict__ z64, const int* __restrict__ cidx, float* __restrict__ out) {
  int m = blockIdx.x;
  __shared__ double sk[256];
  __shared__ int sp[256];
  int tid = threadIdx.x;
  if (tid < KK) { sk[tid] = z64[(size_t)m * KK + tid]; sp[tid] = tid; }
  else { sk[tid] = -INFINITY; sp[tid] = 0x7fffffff; }
  __syncthreads();
  for (int k = 2; k <= 256; k <<= 1) {
    for (int j = k >> 1; j > 0; j >>= 1) {
      int i = tid, l = i ^ j;
      if (l > i) {
        double ka = sk[i], kb2 = sk[l];
        int ia = sp[i], ib = sp[l];
        bool lBefore = (kb2 > ka) || (kb2 == ka && ib < ia);
        bool iBefore = (ka > kb2) || (ka == kb2 && ia < ib);
        bool dir = ((i & k) == 0);
        bool sw = dir ? lBefore : iBefore;
        if (sw) { sk[i] = kb2; sk[l] = ka; sp[i] = ib; sp[l] = ia; }
      }
      __syncthreads();
    }
  }
  if (tid < TOPK) {
    double z = sk[tid];
    out[(size_t)m * TOPK + tid] = (float)(1.0 / (1.0 + exp(-z)));
    out[(size_t)MM * TOPK + (size_t)m * TOPK + tid] = (float)cidx[(size_t)m * KK + sp[tid]];
  }
}

// ---------------- host ----------------
extern "C" void kernel_launch(void* const* d_in, const int* in_sizes, int n_in,
                              void* d_out, int out_size, void* d_ws, size_t ws_size,
                              hipStream_t stream) {
  const float* text  = (const float*)d_in[0];
  const float* kb    = (const float*)d_in[1];
  const float* Wret  = (const float*)d_in[2];
  const float* bret  = (const float*)d_in[3];
  const float* Ws1   = (const float*)d_in[4];
  const float* bs1   = (const float*)d_in[5];
  const float* Ws2   = (const float*)d_in[6];
  const float* bs2   = (const float*)d_in[7];
  const int* msent   = (const int*)d_in[8];
  const int* mstart  = (const int*)d_in[9];
  const int* mlen    = (const int*)d_in[10];
  float* out = (float*)d_out;

  char* ws = (char*)d_ws;
  size_t off = 0;
  auto alloc = [&](size_t bytes) -> void* {
    void* p = ws + off;
    off = (off + bytes + 255) & ~(size_t)255;
    return p;
  };
  double* me64 = (double*)alloc((size_t)MM * DD * 8);
  double* q64  = (double*)alloc((size_t)MM * DD * 8);
  float*  q32  = (float*) alloc((size_t)MM * DD * 4);
  double* mp64 = (double*)alloc((size_t)MM * DD * 8);
  int*    cidx = (int*)   alloc((size_t)MM * KK * 4);
  double* z64  = (double*)alloc((size_t)MM * KK * 8);
  size_t simsoff = off;
  size_t avail = (ws_size > simsoff) ? (ws_size - simsoff) : 0;
  int mg = (int)(avail / ((size_t)NKB * 4));
  if (mg > MM) mg = MM;
  if (mg < 1) mg = 1;
  float* sims = (float*)(ws + simsoff);

  k_mention_emb<<<MM, 256, 0, stream>>>(text, msent, mstart, mlen, me64);
  k_query<<<MM, 256, 0, stream>>>(me64, Wret, bret, q64, q32);
  k_mpart<<<MM, 256, 0, stream>>>(me64, Ws1, mp64);

  for (int mb = 0; mb < MM; mb += mg) {
    int mc = (MM - mb < mg) ? (MM - mb) : mg;
    dim3 gc(NKB / 64, (mc + 63) / 64);
    k_sims<<<gc, 256, 0, stream>>>(q32, kb, sims, mb, mc);
    k_topk<<<mc, 256, 0, stream>>>(sims, kb, q64, mb, cidx);
  }

  k_score<<<(MM * KK) / TM, 256, 0, stream>>>(kb, cidx, mp64, Ws1, bs1, Ws2, bs2, z64);
  k_final<<<MM, 256, 0, stream>>>(z64, cidx, out);
}

// Round 2
// 4250.485 us; speedup vs baseline: 2.1650x; 2.1650x over previous
//
#include <hip/hip_runtime.h>
#include <cfloat>
#include <cmath>
#include <cstdint>

#define DD 768
#define MM 256
#define NKB 200000
#define SLEN 512
#define KK 200      // 2*top_k
#define TOPK 100
#define NBINS 2048
#define CAP 1024
#define MAXMARK 32768
#define DELTA 2e-4

// ---------------- Kernel A: mention embeddings (masked mean, f64) ----------------
__global__ __launch_bounds__(256) void k_mention_emb(
    const float* __restrict__ text, const int* __restrict__ msent,
    const int* __restrict__ mstart, const int* __restrict__ mlen,
    double* __restrict__ me64) {
  int m = blockIdx.x;
  int sent = msent[m], st = mstart[m], ln = mlen[m];
  const float* base = text + (size_t)sent * SLEN * DD;
  for (int d = threadIdx.x; d < DD; d += blockDim.x) {
    double acc = 0.0;
    for (int s = st; s <= st + ln; ++s) acc += (double)base[(size_t)s * DD + d];
    me64[(size_t)m * DD + d] = acc / (double)(ln + 1);
  }
}

// ---------------- Kernel B1: query = me @ W_ret^T + b_ret (f64) ----------------
__global__ __launch_bounds__(256) void k_query(
    const double* __restrict__ me64, const float* __restrict__ Wret,
    const float* __restrict__ bret, double* __restrict__ q64, float* __restrict__ q32) {
  int m = blockIdx.x;
  __shared__ double sme[DD];
  for (int d = threadIdx.x; d < DD; d += blockDim.x) sme[d] = me64[(size_t)m * DD + d];
  __syncthreads();
  for (int e = threadIdx.x; e < DD; e += blockDim.x) {
    double acc = (double)bret[e];
    const float* wr = Wret + (size_t)e * DD;
    for (int d = 0; d < DD; ++d) acc += sme[d] * (double)wr[d];
    q64[(size_t)m * DD + e] = acc;
    q32[(size_t)m * DD + e] = (float)acc;
  }
}

// ---------------- Kernel B2: m_part = me @ Ws1[:D] (f64 + f32 copy) ----------------
__global__ __launch_bounds__(256) void k_mpart(
    const double* __restrict__ me64, const float* __restrict__ Ws1,
    double* __restrict__ mp64, float* __restrict__ mp32) {
  int m = blockIdx.x;
  __shared__ double sme[DD];
  for (int d = threadIdx.x; d < DD; d += blockDim.x) sme[d] = me64[(size_t)m * DD + d];
  __syncthreads();
  for (int e = threadIdx.x; e < DD; e += blockDim.x) {
    double acc = 0.0;
    for (int d = 0; d < DD; ++d) acc += sme[d] * (double)Ws1[(size_t)d * DD + e];
    mp64[(size_t)m * DD + e] = acc;
    mp32[(size_t)m * DD + e] = (float)acc;
  }
}

// ---------------- Kernel C: sims = q32 @ kb^T (f32 SGEMM, 64x64 tile) ----------------
// grid: (m-tiles, n-tiles) so that blocks sharing a kb panel dispatch adjacently (L3 reuse)
__global__ __launch_bounds__(256) void k_sims(
    const float* __restrict__ q32, const float* __restrict__ kb,
    float* __restrict__ sims, int mbase, int mcount) {
  __shared__ float As[32][68];
  __shared__ float Bs[32][68];
  int bn = blockIdx.y;            // 0..3124
  int bm = blockIdx.x;
  int tid = threadIdx.x;
  int tx = tid & 15, ty = tid >> 4;
  const int n0 = bn * 64;
  const int m0 = bm * 64;
  float acc[4][4] = {};
  for (int k0 = 0; k0 < DD; k0 += 32) {
    for (int i = tid; i < 64 * 32; i += 256) {
      int k = i & 31, mm = i >> 5;
      int gm = m0 + mm; if (gm >= mcount) gm = 0;
      As[k][mm] = q32[(size_t)(mbase + gm) * DD + k0 + k];
    }
    for (int i = tid; i < 64 * 32; i += 256) {
      int k = i & 31, nn = i >> 5;
      Bs[k][nn] = kb[(size_t)(n0 + nn) * DD + k0 + k];
    }
    __syncthreads();
#pragma unroll
    for (int k = 0; k < 32; ++k) {
      float4 a = *(const float4*)&As[k][ty * 4];
      float4 b = *(const float4*)&Bs[k][tx * 4];
      acc[0][0] += a.x * b.x; acc[0][1] += a.x * b.y; acc[0][2] += a.x * b.z; acc[0][3] += a.x * b.w;
      acc[1][0] += a.y * b.x; acc[1][1] += a.y * b.y; acc[1][2] += a.y * b.z; acc[1][3] += a.y * b.w;
      acc[2][0] += a.z * b.x; acc[2][1] += a.z * b.y; acc[2][2] += a.z * b.z; acc[2][3] += a.z * b.w;
      acc[3][0] += a.w * b.x; acc[3][1] += a.w * b.y; acc[3][2] += a.w * b.z; acc[3][3] += a.w * b.w;
    }
    __syncthreads();
  }
  for (int i = 0; i < 4; ++i) {
    int gm = m0 + ty * 4 + i;
    if (gm < mcount) {
      float4 v = make_float4(acc[i][0], acc[i][1], acc[i][2], acc[i][3]);
      *(float4*)&sims[(size_t)gm * NKB + n0 + tx * 4] = v;
    }
  }
}

// ------- Kernel D: per-mention top-200 (histogram select + f64 rescore + bitonic) -------
__global__ __launch_bounds__(256) void k_topk(
    const float* __restrict__ sims, const float* __restrict__ kb,
    const double* __restrict__ q64, int mbase, int* __restrict__ cidx) {
  int lm = blockIdx.x;
  int m = mbase + lm;
  const float* row = sims + (size_t)lm * NKB;
  __shared__ float sred[256];
  __shared__ int   hist[NBINS];
  __shared__ int   sbidx[CAP];
  __shared__ double skey[CAP];
  __shared__ double sq[DD];
  __shared__ float sminmax[2];
  __shared__ int   scnt, sbsel;
  int tid = threadIdx.x;

  for (int d = tid; d < DD; d += 256) sq[d] = q64[(size_t)m * DD + d];

  // phase 1: min/max
  float vmin = FLT_MAX, vmax = -FLT_MAX;
  for (int i = tid; i < NKB; i += 256) {
    float v = row[i];
    vmin = fminf(vmin, v); vmax = fmaxf(vmax, v);
  }
  sred[tid] = vmax; __syncthreads();
  for (int s = 128; s > 0; s >>= 1) { if (tid < s) sred[tid] = fmaxf(sred[tid], sred[tid + s]); __syncthreads(); }
  if (tid == 0) sminmax[1] = sred[0];
  __syncthreads();
  sred[tid] = vmin; __syncthreads();
  for (int s = 128; s > 0; s >>= 1) { if (tid < s) sred[tid] = fminf(sred[tid], sred[tid + s]); __syncthreads(); }
  if (tid == 0) sminmax[0] = sred[0];
  for (int i = tid; i < NBINS; i += 256) hist[i] = 0;
  __syncthreads();
  float fmin = sminmax[0], fmax = sminmax[1];
  float scale = (fmax > fmin) ? (float)NBINS / (fmax - fmin) : 0.f;

  // phase 2: histogram
  for (int i = tid; i < NKB; i += 256) {
    int b = (int)((row[i] - fmin) * scale);
    b = b < 0 ? 0 : (b > NBINS - 1 ? NBINS - 1 : b);
    atomicAdd(&hist[b], 1);
  }
  __syncthreads();

  // phase 3: find boundary bin (suffix count >= KK), margin 1 bin
  if (tid == 0) {
    int cum = 0, b = NBINS - 1;
    for (; b >= 0; --b) { cum += hist[b]; if (cum >= KK) break; }
    if (b < 0) b = 0;
    sbsel = (b > 0) ? b - 1 : 0;
    scnt = 0;
  }
  __syncthreads();
  int bsel = sbsel;

  // phase 4: compact candidate indices
  for (int i = tid; i < NKB; i += 256) {
    float v = row[i];
    int b = (int)((v - fmin) * scale);
    b = b < 0 ? 0 : (b > NBINS - 1 ? NBINS - 1 : b);
    if (b >= bsel) {
      int p = atomicAdd(&scnt, 1);
      if (p < CAP) sbidx[p] = i;
    }
  }
  __syncthreads();
  int cnt = scnt; if (cnt > CAP) cnt = CAP;

  // phase 5: exact f64 rescore (one wave per candidate)
  int lane = tid & 63, wid = tid >> 6;
  for (int c = wid; c < cnt; c += 4) {
    const float* krow = kb + (size_t)sbidx[c] * DD;
    double s = 0.0;
    for (int d = lane; d < DD; d += 64) s += sq[d] * (double)krow[d];
    for (int off = 32; off > 0; off >>= 1) s += __shfl_down(s, off, 64);
    if (lane == 0) skey[c] = s;
  }
  for (int c = cnt + tid; c < CAP; c += 256) { skey[c] = -INFINITY; sbidx[c] = 0x7fffffff; }
  __syncthreads();

  // phase 6: bitonic sort CAP elems, desc by key, tie -> smaller idx first
  for (int k = 2; k <= CAP; k <<= 1) {
    for (int j = k >> 1; j > 0; j >>= 1) {
      for (int i = tid; i < CAP; i += 256) {
        int l = i ^ j;
        if (l > i) {
          double ka = skey[i], kb2 = skey[l];
          int ia = sbidx[i], ib = sbidx[l];
          bool lBefore = (kb2 > ka) || (kb2 == ka && ib < ia);
          bool iBefore = (ka > kb2) || (ka == kb2 && ia < ib);
          bool dir = ((i & k) == 0);
          bool sw = dir ? lBefore : iBefore;
          if (sw) { skey[i] = kb2; skey[l] = ka; sbidx[i] = ib; sbidx[l] = ia; }
        }
      }
      __syncthreads();
    }
  }
  for (int c = tid; c < KK; c += 256) cidx[(size_t)m * KK + c] = sbidx[c];
}

// ------- Kernel E: f32 scorer, 64 rows x 64 e-cols register tiled, pz in f64 -------
__global__ __launch_bounds__(256) void k_score32(
    const float* __restrict__ kb, const int* __restrict__ cidx,
    const float* __restrict__ mp32, const float* __restrict__ Ws1,
    const float* __restrict__ bs1, const float* __restrict__ Ws2,
    const float* __restrict__ bs2, double* __restrict__ z64) {
  __shared__ float As[32][68];   // [k][cand]
  __shared__ float Bs[32][68];   // [k][e]
  __shared__ int srow[64];
  __shared__ int smen[64];
  int r0 = blockIdx.x * 64;
  int tid = threadIdx.x;
  if (tid < 64) { int r = r0 + tid; srow[tid] = cidx[r]; smen[tid] = r / KK; }
  __syncthreads();
  int tx = tid & 15, ty = tid >> 4;
  double pz[4] = {0, 0, 0, 0};
  for (int e0 = 0; e0 < DD; e0 += 64) {
    float acc[4][4] = {};
    for (int k0 = 0; k0 < DD; k0 += 32) {
#pragma unroll
      for (int i = 0; i < 8; ++i) {
        int idx = tid + i * 256;
        int c = idx >> 5, k = idx & 31;
        As[k][c] = kb[(size_t)srow[c] * DD + k0 + k];
        int k2 = idx >> 6, e = idx & 63;
        Bs[k2][e] = Ws1[(size_t)(DD + k0 + k2) * DD + e0 + e];
      }
      __syncthreads();
#pragma unroll
      for (int k = 0; k < 32; ++k) {
        float4 a = *(const float4*)&As[k][ty * 4];
        float4 b = *(const float4*)&Bs[k][tx * 4];
        acc[0][0] += a.x * b.x; acc[0][1] += a.x * b.y; acc[0][2] += a.x * b.z; acc[0][3] += a.x * b.w;
        acc[1][0] += a.y * b.x; acc[1][1] += a.y * b.y; acc[1][2] += a.y * b.z; acc[1][3] += a.y * b.w;
        acc[2][0] += a.z * b.x; acc[2][1] += a.z * b.y; acc[2][2] += a.z * b.z; acc[2][3] += a.z * b.w;
        acc[3][0] += a.w * b.x; acc[3][1] += a.w * b.y; acc[3][2] += a.w * b.z; acc[3][3] += a.w * b.w;
      }
      __syncthreads();
    }
    int eb = e0 + tx * 4;
    float4 b1 = *(const float4*)&bs1[eb];
    float4 w2 = *(const float4*)&Ws2[eb];
#pragma unroll
    for (int i = 0; i < 4; ++i) {
      int m = smen[ty * 4 + i];
      float4 mp4 = *(const float4*)(mp32 + (size_t)m * DD + eb);
      float h;
      h = mp4.x + acc[i][0] + b1.x; if (h > 0.f) pz[i] += (double)h * (double)w2.x;
      h = mp4.y + acc[i][1] + b1.y; if (h > 0.f) pz[i] += (double)h * (double)w2.y;
      h = mp4.z + acc[i][2] + b1.z; if (h > 0.f) pz[i] += (double)h * (double)w2.z;
      h = mp4.w + acc[i][3] + b1.w; if (h > 0.f) pz[i] += (double)h * (double)w2.w;
    }
  }
#pragma unroll
  for (int off = 1; off < 16; off <<= 1) {
    pz[0] += __shfl_xor(pz[0], off, 64);
    pz[1] += __shfl_xor(pz[1], off, 64);
    pz[2] += __shfl_xor(pz[2], off, 64);
    pz[3] += __shfl_xor(pz[3], off, 64);
  }
  if (tx == 0) {
    double b2 = (double)bs2[0];
    z64[r0 + ty * 4 + 0] = pz[0] + b2;
    z64[r0 + ty * 4 + 1] = pz[1] + b2;
    z64[r0 + ty * 4 + 2] = pz[2] + b2;
    z64[r0 + ty * 4 + 3] = pz[3] + b2;
  }
}

// ------- Kernel E2: mark ambiguous adjacent pairs (gap < DELTA) in ranks 0..121 -------
__global__ __launch_bounds__(256) void k_mark(
    const double* __restrict__ z64, int* __restrict__ marks, int* __restrict__ mcnt) {
  int m = blockIdx.x;
  __shared__ double sk[256];
  __shared__ int sp[256];
  int tid = threadIdx.x;
  if (tid < KK) { sk[tid] = z64[(size_t)m * KK + tid]; sp[tid] = tid; }
  else { sk[tid] = -INFINITY; sp[tid] = 0x7fffffff; }
  __syncthreads();
  for (int k = 2; k <= 256; k <<= 1) {
    for (int j = k >> 1; j > 0; j >>= 1) {
      int i = tid, l = i ^ j;
      if (l > i) {
        double ka = sk[i], kb2 = sk[l];
        int ia = sp[i], ib = sp[l];
        bool lBefore = (kb2 > ka) || (kb2 == ka && ib < ia);
        bool iBefore = (ka > kb2) || (ka == kb2 && ia < ib);
        bool dir = ((i & k) == 0);
        bool sw = dir ? lBefore : iBefore;
        if (sw) { sk[i] = kb2; sk[l] = ka; sp[i] = ib; sp[l] = ia; }
      }
      __syncthreads();
    }
  }
  if (tid <= 120) {
    if (sk[tid] - sk[tid + 1] < DELTA) {
      int p = atomicAdd(mcnt, 2);
      if (p + 1 < MAXMARK) {
        marks[p]     = m * KK + sp[tid];
        marks[p + 1] = m * KK + sp[tid + 1];
      }
    }
  }
}

// ------- Kernel E3: exact f64 rescore of marked candidates (in-place into z64) -------
__global__ __launch_bounds__(256) void k_rescore(
    const float* __restrict__ kb, const int* __restrict__ cidx,
    const double* __restrict__ mp64, const float* __restrict__ Ws1,
    const float* __restrict__ bs1, const float* __restrict__ Ws2,
    const float* __restrict__ bs2, const int* __restrict__ marks,
    const int* __restrict__ mcnt, double* __restrict__ z64) {
  int cnt = *mcnt; if (cnt > MAXMARK) cnt = MAXMARK;
  __shared__ float sc[DD];
  __shared__ double sred[256];
  int tid = threadIdx.x;
  for (int it = blockIdx.x; it < cnt; it += gridDim.x) {
    int r = marks[it];
    int m = r / KK;
    int row = cidx[r];
    for (int d = tid; d < DD; d += 256) sc[d] = kb[(size_t)row * DD + d];
    __syncthreads();
    double pz = 0.0;
    for (int e = tid; e < DD; e += 256) {
      double a = 0.0;
      for (int d = 0; d < DD; ++d) a += (double)sc[d] * (double)Ws1[(size_t)(DD + d) * DD + e];
      double h = mp64[(size_t)m * DD + e] + a + (double)bs1[e];
      if (h > 0) pz += h * (double)Ws2[e];
    }
    sred[tid] = pz; __syncthreads();
    for (int s = 128; s > 0; s >>= 1) { if (tid < s) sred[tid] += sred[tid + s]; __syncthreads(); }
    if (tid == 0) z64[r] = sred[0] + (double)bs2[0];
    __syncthreads();
  }
}

// ---------------- Kernel F: per-mention top-100 of 200 (bitonic 256) ----------------
__global__ __launch_bounds__(256) void k_final(
    const double* __restrict__ z64, const int* __restrict__ cidx, float* __restrict__ out) {
  int m = blockIdx.x;
  __shared__ double sk[256];
  __shared__ int sp[256];
  int tid = threadIdx.x;
  if (tid < KK) { sk[tid] = z64[(size_t)m * KK + tid]; sp[tid] = tid; }
  else { sk[tid] = -INFINITY; sp[tid] = 0x7fffffff; }
  __syncthreads();
  for (int k = 2; k <= 256; k <<= 1) {
    for (int j = k >> 1; j > 0; j >>= 1) {
      int i = tid, l = i ^ j;
      if (l > i) {
        double ka = sk[i], kb2 = sk[l];
        int ia = sp[i], ib = sp[l];
        bool lBefore = (kb2 > ka) || (kb2 == ka && ib < ia);
        bool iBefore = (ka > kb2) || (ka == kb2 && ia < ib);
        bool dir = ((i & k) == 0);
        bool sw = dir ? lBefore : iBefore;
        if (sw) { sk[i] = kb2; sk[l] = ka; sp[i] = ib; sp[l] = ia; }
      }
      __syncthreads();
    }
  }
  if (tid < TOPK) {
    double z = sk[tid];
    out[(size_t)m * TOPK + tid] = (float)(1.0 / (1.0 + exp(-z)));
    out[(size_t)MM * TOPK + (size_t)m * TOPK + tid] = (float)cidx[(size_t)m * KK + sp[tid]];
  }
}

// ---------------- host ----------------
extern "C" void kernel_launch(void* const* d_in, const int* in_sizes, int n_in,
                              void* d_out, int out_size, void* d_ws, size_t ws_size,
                              hipStream_t stream) {
  const float* text  = (const float*)d_in[0];
  const float* kb    = (const float*)d_in[1];
  const float* Wret  = (const float*)d_in[2];
  const float* bret  = (const float*)d_in[3];
  const float* Ws1   = (const float*)d_in[4];
  const float* bs1   = (const float*)d_in[5];
  const float* Ws2   = (const float*)d_in[6];
  const float* bs2   = (const float*)d_in[7];
  const int* msent   = (const int*)d_in[8];
  const int* mstart  = (const int*)d_in[9];
  const int* mlen    = (const int*)d_in[10];
  float* out = (float*)d_out;

  char* ws = (char*)d_ws;
  size_t off = 0;
  auto alloc = [&](size_t bytes) -> void* {
    void* p = ws + off;
    off = (off + bytes + 255) & ~(size_t)255;
    return p;
  };
  double* me64 = (double*)alloc((size_t)MM * DD * 8);
  double* q64  = (double*)alloc((size_t)MM * DD * 8);
  float*  q32  = (float*) alloc((size_t)MM * DD * 4);
  double* mp64 = (double*)alloc((size_t)MM * DD * 8);
  float*  mp32 = (float*) alloc((size_t)MM * DD * 4);
  int*    cidx = (int*)   alloc((size_t)MM * KK * 4);
  double* z64  = (double*)alloc((size_t)MM * KK * 8);
  int*    marks = (int*)  alloc((size_t)MAXMARK * 4);
  int*    mcnt  = (int*)  alloc(256);
  size_t simsoff = off;
  size_t avail = (ws_size > simsoff) ? (ws_size - simsoff) : 0;
  int mg = (int)(avail / ((size_t)NKB * 4));
  if (mg > MM) mg = MM;
  if (mg < 1) mg = 1;
  float* sims = (float*)(ws + simsoff);

  k_mention_emb<<<MM, 256, 0, stream>>>(text, msent, mstart, mlen, me64);
  k_query<<<MM, 256, 0, stream>>>(me64, Wret, bret, q64, q32);
  k_mpart<<<MM, 256, 0, stream>>>(me64, Ws1, mp64, mp32);

  for (int mb = 0; mb < MM; mb += mg) {
    int mc = (MM - mb < mg) ? (MM - mb) : mg;
    dim3 gc((mc + 63) / 64, NKB / 64);
    k_sims<<<gc, 256, 0, stream>>>(q32, kb, sims, mb, mc);
    k_topk<<<mc, 256, 0, stream>>>(sims, kb, q64, mb, cidx);
  }

  k_score32<<<(MM * KK) / 64, 256, 0, stream>>>(kb, cidx, mp32, Ws1, bs1, Ws2, bs2, z64);
  hipMemsetAsync(mcnt, 0, 4, stream);
  k_mark<<<MM, 256, 0, stream>>>(z64, marks, mcnt);
  k_rescore<<<2048, 256, 0, stream>>>(kb, cidx, mp64, Ws1, bs1, Ws2, bs2, marks, mcnt, z64);
  k_final<<<MM, 256, 0, stream>>>(z64, cidx, out);
}

// Round 3
// 2129.932 us; speedup vs baseline: 4.3206x; 1.9956x over previous
//
#include <hip/hip_runtime.h>
#include <cfloat>
#include <cmath>
#include <cstdint>

#define DD 768
#define MM 256
#define NKB 200000
#define SLEN 512
#define KK 200      // 2*top_k
#define TOPK 100
#define NBINS 2048
#define CAP 2048
#define MARGIN 24
#define MAXMARK 32768
#define DELTA 2e-4

typedef __attribute__((ext_vector_type(8))) short bf16x8;
typedef __attribute__((ext_vector_type(4))) float f32x4;

__device__ __forceinline__ unsigned short f2bf_rne(float x) {
  unsigned u = __float_as_uint(x);
  unsigned r = (u + 0x7FFFu + ((u >> 16) & 1u)) >> 16;
  return (unsigned short)r;
}
__device__ __forceinline__ float bf2f(unsigned short us) {
  return __uint_as_float(((unsigned)us) << 16);
}
__device__ __forceinline__ void splitbf(float x, unsigned short& hi, unsigned short& lo) {
  hi = f2bf_rne(x);
  lo = f2bf_rne(x - bf2f(hi));
}

// ---------------- Kernel A: mention embeddings (masked mean, f64) ----------------
__global__ __launch_bounds__(256) void k_mention_emb(
    const float* __restrict__ text, const int* __restrict__ msent,
    const int* __restrict__ mstart, const int* __restrict__ mlen,
    double* __restrict__ me64) {
  int m = blockIdx.x;
  int sent = msent[m], st = mstart[m], ln = mlen[m];
  const float* base = text + (size_t)sent * SLEN * DD;
  for (int d = threadIdx.x; d < DD; d += blockDim.x) {
    double acc = 0.0;
    for (int s = st; s <= st + ln; ++s) acc += (double)base[(size_t)s * DD + d];
    me64[(size_t)m * DD + d] = acc / (double)(ln + 1);
  }
}

// ---------------- Kernel B1: query = me @ W_ret^T + b_ret (f64) + bf16 copy ----------------
__global__ __launch_bounds__(256) void k_query(
    const double* __restrict__ me64, const float* __restrict__ Wret,
    const float* __restrict__ bret, double* __restrict__ q64,
    unsigned short* __restrict__ qb16) {
  int m = blockIdx.x;
  __shared__ double sme[DD];
  for (int d = threadIdx.x; d < DD; d += blockDim.x) sme[d] = me64[(size_t)m * DD + d];
  __syncthreads();
  for (int e = threadIdx.x; e < DD; e += blockDim.x) {
    double acc = (double)bret[e];
    const float* wr = Wret + (size_t)e * DD;
    for (int d = 0; d < DD; ++d) acc += sme[d] * (double)wr[d];
    q64[(size_t)m * DD + e] = acc;
    qb16[(size_t)m * DD + e] = f2bf_rne((float)acc);
  }
}

// ---------------- Kernel B2: m_part = me @ Ws1[:D] (f64 + f32 copy) ----------------
__global__ __launch_bounds__(256) void k_mpart(
    const double* __restrict__ me64, const float* __restrict__ Ws1,
    double* __restrict__ mp64, float* __restrict__ mp32) {
  int m = blockIdx.x;
  __shared__ double sme[DD];
  for (int d = threadIdx.x; d < DD; d += blockDim.x) sme[d] = me64[(size_t)m * DD + d];
  __syncthreads();
  for (int e = threadIdx.x; e < DD; e += blockDim.x) {
    double acc = 0.0;
    for (int d = 0; d < DD; ++d) acc += sme[d] * (double)Ws1[(size_t)d * DD + e];
    mp64[(size_t)m * DD + e] = acc;
    mp32[(size_t)m * DD + e] = (float)acc;
  }
}

// ---------------- Kernel P: split+transpose Ws1[D:] -> Bt_hi/Bt_lo [e][k] bf16 ----------------
__global__ __launch_bounds__(256) void k_prep(
    const float* __restrict__ Ws1, unsigned short* __restrict__ Bth,
    unsigned short* __restrict__ Btl) {
  int e = blockIdx.x;
  for (int k = threadIdx.x; k < DD; k += 256) {
    float x = Ws1[(size_t)(DD + k) * DD + e];
    unsigned short hi, lo;
    splitbf(x, hi, lo);
    Bth[(size_t)e * DD + k] = hi;
    Btl[(size_t)e * DD + k] = lo;
  }
}

// ---------------- Kernel C: sims = q @ kb^T via bf16 MFMA; output bf16 ----------------
// block: 256 thr (4 waves). Block tile 256m x 64n. Wave w: rows [w*64, w*64+64).
__global__ __launch_bounds__(256) void k_sims_mfma(
    const unsigned short* __restrict__ qb, const float* __restrict__ kb,
    unsigned short* __restrict__ simsb) {
  __shared__ unsigned short As[256 * 32];  // 16 KB, swizzled
  __shared__ unsigned short Bs[64 * 32];   // 4 KB, swizzled
  int n0 = blockIdx.x * 64;
  int tid = threadIdx.x;
  int lane = tid & 63, w = tid >> 6;
  int h = lane >> 4, c = lane & 15;
  f32x4 acc[4][4] = {};
  for (int k0 = 0; k0 < DD; k0 += 32) {
    // stage A (q rows, already bf16): 256x32
#pragma unroll
    for (int i = 0; i < 4; ++i) {
      int idx = tid + i * 256;
      int m = idx >> 2, q4 = idx & 3;
      uint4 v = *(const uint4*)(qb + (size_t)m * DD + k0 + q4 * 8);
      int off = (m * 64 + q4 * 16) ^ ((m & 7) << 4);
      *(uint4*)((char*)As + off) = v;
    }
    // stage B (kb rows f32 -> bf16): 64x32
#pragma unroll
    for (int i = 0; i < 2; ++i) {
      int idx = tid + i * 256;
      int n = idx >> 3, f4 = idx & 7;
      float4 v = *(const float4*)(kb + (size_t)(n0 + n) * DD + k0 + f4 * 4);
      uint2 p;
      p.x = (unsigned)f2bf_rne(v.x) | ((unsigned)f2bf_rne(v.y) << 16);
      p.y = (unsigned)f2bf_rne(v.z) | ((unsigned)f2bf_rne(v.w) << 16);
      int off = (n * 64 + f4 * 8) ^ ((n & 7) << 4);
      *(uint2*)((char*)Bs + off) = p;
    }
    __syncthreads();
    bf16x8 a[4], b[4];
#pragma unroll
    for (int mf = 0; mf < 4; ++mf) {
      int m = w * 64 + mf * 16 + c;
      int off = (m * 64 + h * 16) ^ ((m & 7) << 4);
      a[mf] = *(bf16x8*)((char*)As + off);
    }
#pragma unroll
    for (int nf = 0; nf < 4; ++nf) {
      int n = nf * 16 + c;
      int off = (n * 64 + h * 16) ^ ((n & 7) << 4);
      b[nf] = *(bf16x8*)((char*)Bs + off);
    }
#pragma unroll
    for (int mf = 0; mf < 4; ++mf)
#pragma unroll
      for (int nf = 0; nf < 4; ++nf)
        acc[mf][nf] = __builtin_amdgcn_mfma_f32_16x16x32_bf16(a[mf], b[nf], acc[mf][nf], 0, 0, 0);
    __syncthreads();
  }
  // epilogue: C[row][col]: col = lane&15, row = (lane>>4)*4 + reg
#pragma unroll
  for (int mf = 0; mf < 4; ++mf)
#pragma unroll
    for (int nf = 0; nf < 4; ++nf)
#pragma unroll
      for (int r = 0; r < 4; ++r) {
        int row = w * 64 + mf * 16 + h * 4 + r;
        int col = n0 + nf * 16 + c;
        simsb[(size_t)row * NKB + col] = f2bf_rne(acc[mf][nf][r]);
      }
}

// ------- Kernel D: per-mention top-200 from bf16 sims (hist select + f64 rescore + bitonic) -------
__global__ __launch_bounds__(256) void k_topk(
    const unsigned short* __restrict__ simsb, const float* __restrict__ kb,
    const double* __restrict__ q64, int* __restrict__ cidx) {
  int m = blockIdx.x;
  const unsigned short* row = simsb + (size_t)m * NKB;
  __shared__ float sred[256];
  __shared__ int   hist[NBINS];
  __shared__ int   sbidx[CAP];
  __shared__ double skey[CAP];
  __shared__ double sq[DD];
  __shared__ float sminmax[2];
  __shared__ int   scnt, sbsel;
  int tid = threadIdx.x;

  for (int d = tid; d < DD; d += 256) sq[d] = q64[(size_t)m * DD + d];

  // phase 1: min/max (vectorized 8 bf16/iter)
  float vmin = FLT_MAX, vmax = -FLT_MAX;
  for (int i = tid; i < NKB / 8; i += 256) {
    uint4 v = *(const uint4*)(row + i * 8);
    unsigned ws_[4] = {v.x, v.y, v.z, v.w};
#pragma unroll
    for (int j = 0; j < 4; ++j) {
      float f0 = __uint_as_float(ws_[j] << 16);
      float f1 = __uint_as_float(ws_[j] & 0xFFFF0000u);
      vmin = fminf(vmin, fminf(f0, f1));
      vmax = fmaxf(vmax, fmaxf(f0, f1));
    }
  }
  sred[tid] = vmax; __syncthreads();
  for (int s = 128; s > 0; s >>= 1) { if (tid < s) sred[tid] = fmaxf(sred[tid], sred[tid + s]); __syncthreads(); }
  if (tid == 0) sminmax[1] = sred[0];
  __syncthreads();
  sred[tid] = vmin; __syncthreads();
  for (int s = 128; s > 0; s >>= 1) { if (tid < s) sred[tid] = fminf(sred[tid], sred[tid + s]); __syncthreads(); }
  if (tid == 0) sminmax[0] = sred[0];
  for (int i = tid; i < NBINS; i += 256) hist[i] = 0;
  __syncthreads();
  float fmin = sminmax[0], fmax = sminmax[1];
  float scale = (fmax > fmin) ? (float)NBINS / (fmax - fmin) : 0.f;

  // phase 2: histogram
  for (int i = tid; i < NKB / 8; i += 256) {
    uint4 v = *(const uint4*)(row + i * 8);
    unsigned ws_[4] = {v.x, v.y, v.z, v.w};
#pragma unroll
    for (int j = 0; j < 4; ++j) {
      float f0 = __uint_as_float(ws_[j] << 16);
      float f1 = __uint_as_float(ws_[j] & 0xFFFF0000u);
      int b0 = (int)((f0 - fmin) * scale); b0 = b0 < 0 ? 0 : (b0 > NBINS - 1 ? NBINS - 1 : b0);
      int b1 = (int)((f1 - fmin) * scale); b1 = b1 < 0 ? 0 : (b1 > NBINS - 1 ? NBINS - 1 : b1);
      atomicAdd(&hist[b0], 1);
      atomicAdd(&hist[b1], 1);
    }
  }
  __syncthreads();

  // phase 3: boundary bin (suffix count >= KK) minus MARGIN
  if (tid == 0) {
    int cum = 0, b = NBINS - 1;
    for (; b >= 0; --b) { cum += hist[b]; if (cum >= KK) break; }
    if (b < 0) b = 0;
    int bs = b - MARGIN;
    sbsel = bs > 0 ? bs : 0;
    scnt = 0;
  }
  __syncthreads();
  int bsel = sbsel;

  // phase 4: compact candidate indices
  for (int i = tid; i < NKB / 8; i += 256) {
    uint4 v = *(const uint4*)(row + i * 8);
    unsigned ws_[4] = {v.x, v.y, v.z, v.w};
#pragma unroll
    for (int j = 0; j < 4; ++j) {
      float f0 = __uint_as_float(ws_[j] << 16);
      float f1 = __uint_as_float(ws_[j] & 0xFFFF0000u);
      int b0 = (int)((f0 - fmin) * scale); b0 = b0 < 0 ? 0 : (b0 > NBINS - 1 ? NBINS - 1 : b0);
      int b1 = (int)((f1 - fmin) * scale); b1 = b1 < 0 ? 0 : (b1 > NBINS - 1 ? NBINS - 1 : b1);
      if (b0 >= bsel) { int p = atomicAdd(&scnt, 1); if (p < CAP) sbidx[p] = i * 8 + j * 2; }
      if (b1 >= bsel) { int p = atomicAdd(&scnt, 1); if (p < CAP) sbidx[p] = i * 8 + j * 2 + 1; }
    }
  }
  __syncthreads();
  int cnt = scnt; if (cnt > CAP) cnt = CAP;

  // phase 5: exact f64 rescore (one wave per candidate)
  int lane = tid & 63, wid = tid >> 6;
  for (int cc = wid; cc < cnt; cc += 4) {
    const float* krow = kb + (size_t)sbidx[cc] * DD;
    double s = 0.0;
    for (int d = lane; d < DD; d += 64) s += sq[d] * (double)krow[d];
    for (int off = 32; off > 0; off >>= 1) s += __shfl_down(s, off, 64);
    if (lane == 0) skey[cc] = s;
  }
  for (int cc = cnt + tid; cc < CAP; cc += 256) { skey[cc] = -INFINITY; sbidx[cc] = 0x7fffffff; }
  __syncthreads();

  // phase 6: bitonic sort CAP elems, desc by key, tie -> smaller idx first
  for (int k = 2; k <= CAP; k <<= 1) {
    for (int j = k >> 1; j > 0; j >>= 1) {
      for (int i = tid; i < CAP; i += 256) {
        int l = i ^ j;
        if (l > i) {
          double ka = skey[i], kb2 = skey[l];
          int ia = sbidx[i], ib = sbidx[l];
          bool lBefore = (kb2 > ka) || (kb2 == ka && ib < ia);
          bool iBefore = (ka > kb2) || (ka == kb2 && ia < ib);
          bool dir = ((i & k) == 0);
          bool sw = dir ? lBefore : iBefore;
          if (sw) { skey[i] = kb2; skey[l] = ka; sbidx[i] = ib; sbidx[l] = ia; }
        }
      }
      __syncthreads();
    }
  }
  for (int cc = tid; cc < KK; cc += 256) cidx[(size_t)m * KK + cc] = sbidx[cc];
}

// ------- Kernel E: scorer via 3-pass split-bf16 MFMA (~f32 precision), z in f64 -------
// block 256 thr (4 waves, 2m x 2e wave grid). BM=64 rows, e in 3 passes of 256.
__global__ __launch_bounds__(256) void k_score_mfma(
    const float* __restrict__ kb, const int* __restrict__ cidx,
    const float* __restrict__ mp32, const unsigned short* __restrict__ Bth,
    const unsigned short* __restrict__ Btl, const float* __restrict__ bs1,
    const float* __restrict__ Ws2, const float* __restrict__ bs2,
    double* __restrict__ z64) {
  __shared__ unsigned short Ah[64 * 32], Al[64 * 32];     // 4 KB each
  __shared__ unsigned short Bh[256 * 32], Bl[256 * 32];   // 16 KB each
  __shared__ float smp[2][256], sb1[256], sw2[256];
  __shared__ float zlds[64][2];
  __shared__ int srow[64];
  int r0 = blockIdx.x * 64;
  int tid = threadIdx.x, lane = tid & 63, w = tid >> 6;
  int h = lane >> 4, c = lane & 15;
  int wm0 = (w >> 1) * 32, we0 = (w & 1) * 128;
  if (tid < 64) srow[tid] = cidx[r0 + tid];
  int m0 = r0 / KK, m1 = (r0 + 63) / KK;
  int bnd = (m0 + 1) * KK;
  float zp[2][4] = {};
  for (int e0 = 0; e0 < DD; e0 += 256) {
    __syncthreads();
    // stage per-pass epilogue tables
    smp[0][tid] = mp32[(size_t)m0 * DD + e0 + tid];
    smp[1][tid] = mp32[(size_t)m1 * DD + e0 + tid];
    sb1[tid] = bs1[e0 + tid];
    sw2[tid] = Ws2[e0 + tid];
    f32x4 acc[2][8] = {};
    for (int k0 = 0; k0 < DD; k0 += 32) {
      __syncthreads();
      // stage A: gather 64 cand rows x 32k f32 -> split hi/lo bf16
#pragma unroll
      for (int i = 0; i < 2; ++i) {
        int idx = tid + i * 256;
        int rr = idx >> 3, f4 = idx & 7;
        float4 v = *(const float4*)(kb + (size_t)srow[rr] * DD + k0 + f4 * 4);
        unsigned short h0, h1, h2, h3, l0, l1, l2, l3;
        splitbf(v.x, h0, l0); splitbf(v.y, h1, l1);
        splitbf(v.z, h2, l2); splitbf(v.w, h3, l3);
        uint2 ph, pl;
        ph.x = (unsigned)h0 | ((unsigned)h1 << 16); ph.y = (unsigned)h2 | ((unsigned)h3 << 16);
        pl.x = (unsigned)l0 | ((unsigned)l1 << 16); pl.y = (unsigned)l2 | ((unsigned)l3 << 16);
        int off = (rr * 64 + f4 * 8) ^ ((rr & 7) << 4);
        *(uint2*)((char*)Ah + off) = ph;
        *(uint2*)((char*)Al + off) = pl;
      }
      // stage B: Ws1 split panels (e-major [e][k] bf16)
#pragma unroll
      for (int i = 0; i < 4; ++i) {
        int idx = tid + i * 256;
        int e = idx >> 2, k8 = idx & 3;
        uint4 vh = *(const uint4*)(Bth + (size_t)(e0 + e) * DD + k0 + k8 * 8);
        uint4 vl = *(const uint4*)(Btl + (size_t)(e0 + e) * DD + k0 + k8 * 8);
        int off = (e * 64 + k8 * 16) ^ ((e & 7) << 4);
        *(uint4*)((char*)Bh + off) = vh;
        *(uint4*)((char*)Bl + off) = vl;
      }
      __syncthreads();
      bf16x8 ah[2], al[2];
#pragma unroll
      for (int mf = 0; mf < 2; ++mf) {
        int rr = wm0 + mf * 16 + c;
        int off = (rr * 64 + h * 16) ^ ((rr & 7) << 4);
        ah[mf] = *(bf16x8*)((char*)Ah + off);
        al[mf] = *(bf16x8*)((char*)Al + off);
      }
#pragma unroll
      for (int nf = 0; nf < 8; ++nf) {
        int e = we0 + nf * 16 + c;
        int off = (e * 64 + h * 16) ^ ((e & 7) << 4);
        bf16x8 bh = *(bf16x8*)((char*)Bh + off);
        bf16x8 bl = *(bf16x8*)((char*)Bl + off);
#pragma unroll
        for (int mf = 0; mf < 2; ++mf) {
          acc[mf][nf] = __builtin_amdgcn_mfma_f32_16x16x32_bf16(ah[mf], bh, acc[mf][nf], 0, 0, 0);
          acc[mf][nf] = __builtin_amdgcn_mfma_f32_16x16x32_bf16(ah[mf], bl, acc[mf][nf], 0, 0, 0);
          acc[mf][nf] = __builtin_amdgcn_mfma_f32_16x16x32_bf16(al[mf], bh, acc[mf][nf], 0, 0, 0);
        }
      }
    }
    // epilogue for this e-pass: h = U + mp + b1; relu; z += h*w2
#pragma unroll
    for (int mf = 0; mf < 2; ++mf)
#pragma unroll
      for (int nf = 0; nf < 8; ++nf)
#pragma unroll
        for (int r = 0; r < 4; ++r) {
          int slot = wm0 + mf * 16 + h * 4 + r;
          int el = we0 + nf * 16 + c;
          int sel = (r0 + slot >= bnd) ? 1 : 0;
          float hh = acc[mf][nf][r] + smp[sel][el] + sb1[el];
          if (hh > 0.f) zp[mf][r] += hh * sw2[el];
        }
  }
  // reduce over the 16 col-lanes (c bits)
#pragma unroll
  for (int mf = 0; mf < 2; ++mf)
#pragma unroll
    for (int r = 0; r < 4; ++r) {
      float v = zp[mf][r];
      v += __shfl_xor(v, 1, 64);
      v += __shfl_xor(v, 2, 64);
      v += __shfl_xor(v, 4, 64);
      v += __shfl_xor(v, 8, 64);
      zp[mf][r] = v;
    }
  __syncthreads();
  if (c == 0) {
#pragma unroll
    for (int mf = 0; mf < 2; ++mf)
#pragma unroll
      for (int r = 0; r < 4; ++r)
        zlds[wm0 + mf * 16 + h * 4 + r][w & 1] = zp[mf][r];
  }
  __syncthreads();
  if (tid < 64)
    z64[r0 + tid] = (double)(zlds[tid][0] + zlds[tid][1]) + (double)bs2[0];
}

// ------- Kernel E2: mark ambiguous adjacent pairs (gap < DELTA) in ranks 0..121 -------
__global__ __launch_bounds__(256) void k_mark(
    const double* __restrict__ z64, int* __restrict__ marks, int* __restrict__ mcnt) {
  int m = blockIdx.x;
  __shared__ double sk[256];
  __shared__ int sp[256];
  int tid = threadIdx.x;
  if (tid < KK) { sk[tid] = z64[(size_t)m * KK + tid]; sp[tid] = tid; }
  else { sk[tid] = -INFINITY; sp[tid] = 0x7fffffff; }
  __syncthreads();
  for (int k = 2; k <= 256; k <<= 1) {
    for (int j = k >> 1; j > 0; j >>= 1) {
      int i = tid, l = i ^ j;
      if (l > i) {
        double ka = sk[i], kb2 = sk[l];
        int ia = sp[i], ib = sp[l];
        bool lBefore = (kb2 > ka) || (kb2 == ka && ib < ia);
        bool iBefore = (ka > kb2) || (ka == kb2 && ia < ib);
        bool dir = ((i & k) == 0);
        bool sw = dir ? lBefore : iBefore;
        if (sw) { sk[i] = kb2; sk[l] = ka; sp[i] = ib; sp[l] = ia; }
      }
      __syncthreads();
    }
  }
  if (tid <= 120) {
    if (sk[tid] - sk[tid + 1] < DELTA) {
      int p = atomicAdd(mcnt, 2);
      if (p + 1 < MAXMARK) {
        marks[p]     = m * KK + sp[tid];
        marks[p + 1] = m * KK + sp[tid + 1];
      }
    }
  }
}

// ------- Kernel E3: exact f64 rescore of marked candidates (in-place into z64) -------
__global__ __launch_bounds__(256) void k_rescore(
    const float* __restrict__ kb, const int* __restrict__ cidx,
    const double* __restrict__ mp64, const float* __restrict__ Ws1,
    const float* __restrict__ bs1, const float* __restrict__ Ws2,
    const float* __restrict__ bs2, const int* __restrict__ marks,
    const int* __restrict__ mcnt, double* __restrict__ z64) {
  int cnt = *mcnt; if (cnt > MAXMARK) cnt = MAXMARK;
  __shared__ float sc[DD];
  __shared__ double sred[256];
  int tid = threadIdx.x;
  for (int it = blockIdx.x; it < cnt; it += gridDim.x) {
    int r = marks[it];
    int m = r / KK;
    int row = cidx[r];
    for (int d = tid; d < DD; d += 256) sc[d] = kb[(size_t)row * DD + d];
    __syncthreads();
    double pz = 0.0;
    for (int e = tid; e < DD; e += 256) {
      double a = 0.0;
      for (int d = 0; d < DD; ++d) a += (double)sc[d] * (double)Ws1[(size_t)(DD + d) * DD + e];
      double hv = mp64[(size_t)m * DD + e] + a + (double)bs1[e];
      if (hv > 0) pz += hv * (double)Ws2[e];
    }
    sred[tid] = pz; __syncthreads();
    for (int s = 128; s > 0; s >>= 1) { if (tid < s) sred[tid] += sred[tid + s]; __syncthreads(); }
    if (tid == 0) z64[r] = sred[0] + (double)bs2[0];
    __syncthreads();
  }
}

// ---------------- Kernel F: per-mention top-100 of 200 (bitonic 256) ----------------
__global__ __launch_bounds__(256) void k_final(
    const double* __restrict__ z64, const int* __restrict__ cidx, float* __restrict__ out) {
  int m = blockIdx.x;
  __shared__ double sk[256];
  __shared__ int sp[256];
  int tid = threadIdx.x;
  if (tid < KK) { sk[tid] = z64[(size_t)m * KK + tid]; sp[tid] = tid; }
  else { sk[tid] = -INFINITY; sp[tid] = 0x7fffffff; }
  __syncthreads();
  for (int k = 2; k <= 256; k <<= 1) {
    for (int j = k >> 1; j > 0; j >>= 1) {
      int i = tid, l = i ^ j;
      if (l > i) {
        double ka = sk[i], kb2 = sk[l];
        int ia = sp[i], ib = sp[l];
        bool lBefore = (kb2 > ka) || (kb2 == ka && ib < ia);
        bool iBefore = (ka > kb2) || (ka == kb2 && ia < ib);
        bool dir = ((i & k) == 0);
        bool sw = dir ? lBefore : iBefore;
        if (sw) { sk[i] = kb2; sk[l] = ka; sp[i] = ib; sp[l] = ia; }
      }
      __syncthreads();
    }
  }
  if (tid < TOPK) {
    double z = sk[tid];
    out[(size_t)m * TOPK + tid] = (float)(1.0 / (1.0 + exp(-z)));
    out[(size_t)MM * TOPK + (size_t)m * TOPK + tid] = (float)cidx[(size_t)m * KK + sp[tid]];
  }
}

// ---------------- host ----------------
extern "C" void kernel_launch(void* const* d_in, const int* in_sizes, int n_in,
                              void* d_out, int out_size, void* d_ws, size_t ws_size,
                              hipStream_t stream) {
  const float* text  = (const float*)d_in[0];
  const float* kb    = (const float*)d_in[1];
  const float* Wret  = (const float*)d_in[2];
  const float* bret  = (const float*)d_in[3];
  const float* Ws1   = (const float*)d_in[4];
  const float* bs1   = (const float*)d_in[5];
  const float* Ws2   = (const float*)d_in[6];
  const float* bs2   = (const float*)d_in[7];
  const int* msent   = (const int*)d_in[8];
  const int* mstart  = (const int*)d_in[9];
  const int* mlen    = (const int*)d_in[10];
  float* out = (float*)d_out;

  char* ws = (char*)d_ws;
  size_t off = 0;
  auto alloc = [&](size_t bytes) -> void* {
    void* p = ws + off;
    off = (off + bytes + 255) & ~(size_t)255;
    return p;
  };
  double* me64 = (double*)alloc((size_t)MM * DD * 8);
  double* q64  = (double*)alloc((size_t)MM * DD * 8);
  unsigned short* qb16 = (unsigned short*)alloc((size_t)MM * DD * 2);
  double* mp64 = (double*)alloc((size_t)MM * DD * 8);
  float*  mp32 = (float*) alloc((size_t)MM * DD * 4);
  int*    cidx = (int*)   alloc((size_t)MM * KK * 4);
  double* z64  = (double*)alloc((size_t)MM * KK * 8);
  int*    marks = (int*)  alloc((size_t)MAXMARK * 4);
  int*    mcnt  = (int*)  alloc(256);
  unsigned short* Bth = (unsigned short*)alloc((size_t)DD * DD * 2);
  unsigned short* Btl = (unsigned short*)alloc((size_t)DD * DD * 2);
  unsigned short* simsb = (unsigned short*)alloc((size_t)MM * NKB * 2);
  (void)ws_size;

  k_mention_emb<<<MM, 256, 0, stream>>>(text, msent, mstart, mlen, me64);
  k_query<<<MM, 256, 0, stream>>>(me64, Wret, bret, q64, qb16);
  k_mpart<<<MM, 256, 0, stream>>>(me64, Ws1, mp64, mp32);
  k_prep<<<DD, 256, 0, stream>>>(Ws1, Bth, Btl);

  k_sims_mfma<<<NKB / 64, 256, 0, stream>>>(qb16, kb, simsb);
  k_topk<<<MM, 256, 0, stream>>>(simsb, kb, q64, cidx);

  k_score_mfma<<<(MM * KK) / 64, 256, 0, stream>>>(kb, cidx, mp32, Bth, Btl, bs1, Ws2, bs2, z64);
  hipMemsetAsync(mcnt, 0, 4, stream);
  k_mark<<<MM, 256, 0, stream>>>(z64, marks, mcnt);
  k_rescore<<<2048, 256, 0, stream>>>(kb, cidx, mp64, Ws1, bs1, Ws2, bs2, marks, mcnt, z64);
  k_final<<<MM, 256, 0, stream>>>(z64, cidx, out);
}

// Round 4
// 1956.459 us; speedup vs baseline: 4.7036x; 1.0887x over previous
//
#include <hip/hip_runtime.h>
#include <cfloat>
#include <cmath>
#include <cstdint>

#define DD 768
#define MM 256
#define NKB 200000
#define SLEN 512
#define KK 200      // 2*top_k
#define TOPK 100
#define SURV_CAP 1024
#define RESC 232
#define THRC 2.70f
#define MAXMARK 32768
#define DELTA 2e-4

typedef __attribute__((ext_vector_type(8))) short bf16x8;
typedef __attribute__((ext_vector_type(4))) float f32x4;

__device__ __forceinline__ unsigned short f2bf_rne(float x) {
  unsigned u = __float_as_uint(x);
  unsigned r = (u + 0x7FFFu + ((u >> 16) & 1u)) >> 16;
  return (unsigned short)r;
}
__device__ __forceinline__ float bf2f(unsigned short us) {
  return __uint_as_float(((unsigned)us) << 16);
}
__device__ __forceinline__ void splitbf(float x, unsigned short& hi, unsigned short& lo) {
  hi = f2bf_rne(x);
  lo = f2bf_rne(x - bf2f(hi));
}

// ---------------- Kernel A: mention embeddings (masked mean, f64) ----------------
__global__ __launch_bounds__(256) void k_mention_emb(
    const float* __restrict__ text, const int* __restrict__ msent,
    const int* __restrict__ mstart, const int* __restrict__ mlen,
    double* __restrict__ me64) {
  int m = blockIdx.x;
  int sent = msent[m], st = mstart[m], ln = mlen[m];
  const float* base = text + (size_t)sent * SLEN * DD;
  for (int d = threadIdx.x; d < DD; d += blockDim.x) {
    double acc = 0.0;
    for (int s = st; s <= st + ln; ++s) acc += (double)base[(size_t)s * DD + d];
    me64[(size_t)m * DD + d] = acc / (double)(ln + 1);
  }
}

// ------- Kernel B1: query = me @ W_ret^T + b_ret (f64) + bf16 copy + threshold -------
__global__ __launch_bounds__(256) void k_query(
    const double* __restrict__ me64, const float* __restrict__ Wret,
    const float* __restrict__ bret, double* __restrict__ q64,
    unsigned short* __restrict__ qb16, float* __restrict__ tthr) {
  int m = blockIdx.x;
  __shared__ double sme[DD];
  __shared__ float snorm[256];
  for (int d = threadIdx.x; d < DD; d += blockDim.x) sme[d] = me64[(size_t)m * DD + d];
  __syncthreads();
  float nloc = 0.f;
  for (int e = threadIdx.x; e < DD; e += blockDim.x) {
    double acc = (double)bret[e];
    const float* wr = Wret + (size_t)e * DD;
    for (int d = 0; d < DD; ++d) acc += sme[d] * (double)wr[d];
    q64[(size_t)m * DD + e] = acc;
    qb16[(size_t)m * DD + e] = f2bf_rne((float)acc);
    nloc += (float)(acc * acc);
  }
  snorm[threadIdx.x] = nloc; __syncthreads();
  for (int s = 128; s > 0; s >>= 1) {
    if (threadIdx.x < s) snorm[threadIdx.x] += snorm[threadIdx.x + s];
    __syncthreads();
  }
  if (threadIdx.x == 0) tthr[m] = THRC * sqrtf(snorm[0]);
}

// ---------------- Kernel B2: m_part = me @ Ws1[:D] (f64 + f32 copy) ----------------
__global__ __launch_bounds__(256) void k_mpart(
    const double* __restrict__ me64, const float* __restrict__ Ws1,
    double* __restrict__ mp64, float* __restrict__ mp32) {
  int m = blockIdx.x;
  __shared__ double sme[DD];
  for (int d = threadIdx.x; d < DD; d += blockDim.x) sme[d] = me64[(size_t)m * DD + d];
  __syncthreads();
  for (int e = threadIdx.x; e < DD; e += blockDim.x) {
    double acc = 0.0;
    for (int d = 0; d < DD; ++d) acc += sme[d] * (double)Ws1[(size_t)d * DD + e];
    mp64[(size_t)m * DD + e] = acc;
    mp32[(size_t)m * DD + e] = (float)acc;
  }
}

// ---------------- Kernel P: split+transpose Ws1[D:] -> Bt_hi/Bt_lo [e][k] bf16 ----------------
__global__ __launch_bounds__(256) void k_prep(
    const float* __restrict__ Ws1, unsigned short* __restrict__ Bth,
    unsigned short* __restrict__ Btl) {
  int e = blockIdx.x;
  for (int k = threadIdx.x; k < DD; k += 256) {
    float x = Ws1[(size_t)(DD + k) * DD + e];
    unsigned short hi, lo;
    splitbf(x, hi, lo);
    Bth[(size_t)e * DD + k] = hi;
    Btl[(size_t)e * DD + k] = lo;
  }
}

// ------- Kernel C: sims = q @ kb^T via bf16 MFMA; threshold-compact survivors -------
// block: 256 thr (4 waves). Block tile 256m x 64n. Wave w: rows [w*64, w*64+64).
__global__ __launch_bounds__(256) void k_sims_mfma(
    const unsigned short* __restrict__ qb, const float* __restrict__ kb,
    const float* __restrict__ tthr, int* __restrict__ gcnt,
    uint2* __restrict__ gcand) {
  __shared__ unsigned short As[256 * 32];  // 16 KB, swizzled
  __shared__ unsigned short Bs[64 * 32];   // 4 KB, swizzled
  __shared__ float sthr[256];
  int n0 = blockIdx.x * 64;
  int tid = threadIdx.x;
  int lane = tid & 63, w = tid >> 6;
  int h = lane >> 4, c = lane & 15;
  sthr[tid] = tthr[tid];
  f32x4 acc[4][4] = {};
  for (int k0 = 0; k0 < DD; k0 += 32) {
    // stage A (q rows, already bf16): 256x32
#pragma unroll
    for (int i = 0; i < 4; ++i) {
      int idx = tid + i * 256;
      int m = idx >> 2, q4 = idx & 3;
      uint4 v = *(const uint4*)(qb + (size_t)m * DD + k0 + q4 * 8);
      int off = (m * 64 + q4 * 16) ^ ((m & 7) << 4);
      *(uint4*)((char*)As + off) = v;
    }
    // stage B (kb rows f32 -> bf16): 64x32
#pragma unroll
    for (int i = 0; i < 2; ++i) {
      int idx = tid + i * 256;
      int n = idx >> 3, f4 = idx & 7;
      float4 v = *(const float4*)(kb + (size_t)(n0 + n) * DD + k0 + f4 * 4);
      uint2 p;
      p.x = (unsigned)f2bf_rne(v.x) | ((unsigned)f2bf_rne(v.y) << 16);
      p.y = (unsigned)f2bf_rne(v.z) | ((unsigned)f2bf_rne(v.w) << 16);
      int off = (n * 64 + f4 * 8) ^ ((n & 7) << 4);
      *(uint2*)((char*)Bs + off) = p;
    }
    __syncthreads();
    bf16x8 a[4], b[4];
#pragma unroll
    for (int mf = 0; mf < 4; ++mf) {
      int m = w * 64 + mf * 16 + c;
      int off = (m * 64 + h * 16) ^ ((m & 7) << 4);
      a[mf] = *(bf16x8*)((char*)As + off);
    }
#pragma unroll
    for (int nf = 0; nf < 4; ++nf) {
      int n = nf * 16 + c;
      int off = (n * 64 + h * 16) ^ ((n & 7) << 4);
      b[nf] = *(bf16x8*)((char*)Bs + off);
    }
#pragma unroll
    for (int mf = 0; mf < 4; ++mf)
#pragma unroll
      for (int nf = 0; nf < 4; ++nf)
        acc[mf][nf] = __builtin_amdgcn_mfma_f32_16x16x32_bf16(a[mf], b[nf], acc[mf][nf], 0, 0, 0);
    __syncthreads();
  }
  // epilogue: C[row][col]: col = lane&15, row = (lane>>4)*4 + reg
  // compact survivors (v > thr[row]) into per-mention global lists
#pragma unroll
  for (int mf = 0; mf < 4; ++mf)
#pragma unroll
    for (int nf = 0; nf < 4; ++nf)
#pragma unroll
      for (int r = 0; r < 4; ++r) {
        int row = w * 64 + mf * 16 + h * 4 + r;
        int col = n0 + nf * 16 + c;
        float v = acc[mf][nf][r];
        if (v > sthr[row]) {
          int p = atomicAdd(&gcnt[row], 1);
          if (p < SURV_CAP) gcand[(size_t)row * SURV_CAP + p] = make_uint2(__float_as_uint(v), (unsigned)col);
        }
      }
}

// ------- Kernel D: per-mention select top-200: sort survivors by f32 sims,
//         f64-rescore top RESC, exact sort, emit in sims-desc order -------
__global__ __launch_bounds__(256) void k_select(
    const uint2* __restrict__ gcand, const int* __restrict__ gcnt,
    const float* __restrict__ kb, const double* __restrict__ q64,
    int* __restrict__ cidx) {
  int m = blockIdx.x;
  __shared__ float skf[SURV_CAP];
  __shared__ int   sidx[SURV_CAP];
  __shared__ double sq[DD];
  __shared__ double skey[256];
  __shared__ int    skidx[256];
  int tid = threadIdx.x;
  int cnt = gcnt[m]; if (cnt > SURV_CAP) cnt = SURV_CAP;
  for (int d = tid; d < DD; d += 256) sq[d] = q64[(size_t)m * DD + d];
  for (int i = tid; i < SURV_CAP; i += 256) {
    if (i < cnt) {
      uint2 v = gcand[(size_t)m * SURV_CAP + i];
      skf[i] = __uint_as_float(v.x);
      sidx[i] = (int)v.y;
    } else { skf[i] = -FLT_MAX; sidx[i] = 0x7fffffff; }
  }
  __syncthreads();
  // bitonic sort 1024 desc by skf, tie -> smaller idx
  for (int k = 2; k <= SURV_CAP; k <<= 1) {
    for (int j = k >> 1; j > 0; j >>= 1) {
      for (int i = tid; i < SURV_CAP; i += 256) {
        int l = i ^ j;
        if (l > i) {
          float ka = skf[i], kb2 = skf[l];
          int ia = sidx[i], ib = sidx[l];
          bool lBefore = (kb2 > ka) || (kb2 == ka && ib < ia);
          bool iBefore = (ka > kb2) || (ka == kb2 && ia < ib);
          bool dir = ((i & k) == 0);
          bool sw = dir ? lBefore : iBefore;
          if (sw) { skf[i] = kb2; skf[l] = ka; sidx[i] = ib; sidx[l] = ia; }
        }
      }
      __syncthreads();
    }
  }
  // f64 rescore top RESC (one wave per candidate)
  int lane = tid & 63, wv = tid >> 6;
  for (int cpos = wv; cpos < RESC; cpos += 4) {
    int ci = sidx[cpos];
    double s;
    if (ci < NKB) {
      const float* krow = kb + (size_t)ci * DD;
      double acc = 0.0;
      for (int d = lane; d < DD; d += 64) acc += sq[d] * (double)krow[d];
      for (int off2 = 32; off2 > 0; off2 >>= 1) acc += __shfl_down(acc, off2, 64);
      s = acc;
    } else s = -INFINITY;
    if (lane == 0) { skey[cpos] = s; skidx[cpos] = ci; }
  }
  if (tid >= RESC && tid < 256) { skey[tid] = -INFINITY; skidx[tid] = 0x7fffffff; }
  __syncthreads();
  // bitonic sort 256 desc by f64 key, tie -> smaller idx
  for (int k = 2; k <= 256; k <<= 1) {
    for (int j = k >> 1; j > 0; j >>= 1) {
      int i = tid, l = i ^ j;
      if (l > i) {
        double ka = skey[i], kb2 = skey[l];
        int ia = skidx[i], ib = skidx[l];
        bool lBefore = (kb2 > ka) || (kb2 == ka && ib < ia);
        bool iBefore = (ka > kb2) || (ka == kb2 && ia < ib);
        bool dir = ((i & k) == 0);
        bool sw = dir ? lBefore : iBefore;
        if (sw) { skey[i] = kb2; skey[l] = ka; skidx[i] = ib; skidx[l] = ia; }
      }
      __syncthreads();
    }
  }
  for (int cc = tid; cc < KK; cc += 256) {
    int v = skidx[cc];
    cidx[(size_t)m * KK + cc] = (v < NKB) ? v : 0;
  }
}

// ------- Kernel E: scorer via 3-pass split-bf16 MFMA (~f32 precision), z in f64 -------
// block 256 thr (4 waves, 2m x 2e wave grid). BM=64 rows, e in 3 passes of 256.
__global__ __launch_bounds__(256) void k_score_mfma(
    const float* __restrict__ kb, const int* __restrict__ cidx,
    const float* __restrict__ mp32, const unsigned short* __restrict__ Bth,
    const unsigned short* __restrict__ Btl, const float* __restrict__ bs1,
    const float* __restrict__ Ws2, const float* __restrict__ bs2,
    double* __restrict__ z64) {
  __shared__ unsigned short Ah[64 * 32], Al[64 * 32];     // 4 KB each
  __shared__ unsigned short Bh[256 * 32], Bl[256 * 32];   // 16 KB each
  __shared__ float smp[2][256], sb1[256], sw2[256];
  __shared__ float zlds[64][2];
  __shared__ int srow[64];
  int r0 = blockIdx.x * 64;
  int tid = threadIdx.x, lane = tid & 63, w = tid >> 6;
  int h = lane >> 4, c = lane & 15;
  int wm0 = (w >> 1) * 32, we0 = (w & 1) * 128;
  if (tid < 64) srow[tid] = cidx[r0 + tid];
  int m0 = r0 / KK, m1 = (r0 + 63) / KK;
  int bnd = (m0 + 1) * KK;
  float zp[2][4] = {};
  for (int e0 = 0; e0 < DD; e0 += 256) {
    __syncthreads();
    // stage per-pass epilogue tables
    smp[0][tid] = mp32[(size_t)m0 * DD + e0 + tid];
    smp[1][tid] = mp32[(size_t)m1 * DD + e0 + tid];
    sb1[tid] = bs1[e0 + tid];
    sw2[tid] = Ws2[e0 + tid];
    f32x4 acc[2][8] = {};
    for (int k0 = 0; k0 < DD; k0 += 32) {
      __syncthreads();
      // stage A: gather 64 cand rows x 32k f32 -> split hi/lo bf16
#pragma unroll
      for (int i = 0; i < 2; ++i) {
        int idx = tid + i * 256;
        int rr = idx >> 3, f4 = idx & 7;
        float4 v = *(const float4*)(kb + (size_t)srow[rr] * DD + k0 + f4 * 4);
        unsigned short h0, h1, h2, h3, l0, l1, l2, l3;
        splitbf(v.x, h0, l0); splitbf(v.y, h1, l1);
        splitbf(v.z, h2, l2); splitbf(v.w, h3, l3);
        uint2 ph, pl;
        ph.x = (unsigned)h0 | ((unsigned)h1 << 16); ph.y = (unsigned)h2 | ((unsigned)h3 << 16);
        pl.x = (unsigned)l0 | ((unsigned)l1 << 16); pl.y = (unsigned)l2 | ((unsigned)l3 << 16);
        int off = (rr * 64 + f4 * 8) ^ ((rr & 7) << 4);
        *(uint2*)((char*)Ah + off) = ph;
        *(uint2*)((char*)Al + off) = pl;
      }
      // stage B: Ws1 split panels (e-major [e][k] bf16)
#pragma unroll
      for (int i = 0; i < 4; ++i) {
        int idx = tid + i * 256;
        int e = idx >> 2, k8 = idx & 3;
        uint4 vh = *(const uint4*)(Bth + (size_t)(e0 + e) * DD + k0 + k8 * 8);
        uint4 vl = *(const uint4*)(Btl + (size_t)(e0 + e) * DD + k0 + k8 * 8);
        int off = (e * 64 + k8 * 16) ^ ((e & 7) << 4);
        *(uint4*)((char*)Bh + off) = vh;
        *(uint4*)((char*)Bl + off) = vl;
      }
      __syncthreads();
      bf16x8 ah[2], al[2];
#pragma unroll
      for (int mf = 0; mf < 2; ++mf) {
        int rr = wm0 + mf * 16 + c;
        int off = (rr * 64 + h * 16) ^ ((rr & 7) << 4);
        ah[mf] = *(bf16x8*)((char*)Ah + off);
        al[mf] = *(bf16x8*)((char*)Al + off);
      }
#pragma unroll
      for (int nf = 0; nf < 8; ++nf) {
        int e = we0 + nf * 16 + c;
        int off = (e * 64 + h * 16) ^ ((e & 7) << 4);
        bf16x8 bh = *(bf16x8*)((char*)Bh + off);
        bf16x8 bl = *(bf16x8*)((char*)Bl + off);
#pragma unroll
        for (int mf = 0; mf < 2; ++mf) {
          acc[mf][nf] = __builtin_amdgcn_mfma_f32_16x16x32_bf16(ah[mf], bh, acc[mf][nf], 0, 0, 0);
          acc[mf][nf] = __builtin_amdgcn_mfma_f32_16x16x32_bf16(ah[mf], bl, acc[mf][nf], 0, 0, 0);
          acc[mf][nf] = __builtin_amdgcn_mfma_f32_16x16x32_bf16(al[mf], bh, acc[mf][nf], 0, 0, 0);
        }
      }
    }
    // epilogue for this e-pass: h = U + mp + b1; relu; z += h*w2
#pragma unroll
    for (int mf = 0; mf < 2; ++mf)
#pragma unroll
      for (int nf = 0; nf < 8; ++nf)
#pragma unroll
        for (int r = 0; r < 4; ++r) {
          int slot = wm0 + mf * 16 + h * 4 + r;
          int el = we0 + nf * 16 + c;
          int sel = (r0 + slot >= bnd) ? 1 : 0;
          float hh = acc[mf][nf][r] + smp[sel][el] + sb1[el];
          if (hh > 0.f) zp[mf][r] += hh * sw2[el];
        }
  }
  // reduce over the 16 col-lanes (c bits)
#pragma unroll
  for (int mf = 0; mf < 2; ++mf)
#pragma unroll
    for (int r = 0; r < 4; ++r) {
      float v = zp[mf][r];
      v += __shfl_xor(v, 1, 64);
      v += __shfl_xor(v, 2, 64);
      v += __shfl_xor(v, 4, 64);
      v += __shfl_xor(v, 8, 64);
      zp[mf][r] = v;
    }
  __syncthreads();
  if (c == 0) {
#pragma unroll
    for (int mf = 0; mf < 2; ++mf)
#pragma unroll
      for (int r = 0; r < 4; ++r)
        zlds[wm0 + mf * 16 + h * 4 + r][w & 1] = zp[mf][r];
  }
  __syncthreads();
  if (tid < 64)
    z64[r0 + tid] = (double)(zlds[tid][0] + zlds[tid][1]) + (double)bs2[0];
}

// ------- Kernel E2: mark ambiguous adjacent pairs (gap < DELTA) in ranks 0..121 -------
__global__ __launch_bounds__(256) void k_mark(
    const double* __restrict__ z64, int* __restrict__ marks, int* __restrict__ mcnt) {
  int m = blockIdx.x;
  __shared__ double sk[256];
  __shared__ int sp[256];
  int tid = threadIdx.x;
  if (tid < KK) { sk[tid] = z64[(size_t)m * KK + tid]; sp[tid] = tid; }
  else { sk[tid] = -INFINITY; sp[tid] = 0x7fffffff; }
  __syncthreads();
  for (int k = 2; k <= 256; k <<= 1) {
    for (int j = k >> 1; j > 0; j >>= 1) {
      int i = tid, l = i ^ j;
      if (l > i) {
        double ka = sk[i], kb2 = sk[l];
        int ia = sp[i], ib = sp[l];
        bool lBefore = (kb2 > ka) || (kb2 == ka && ib < ia);
        bool iBefore = (ka > kb2) || (ka == kb2 && ia < ib);
        bool dir = ((i & k) == 0);
        bool sw = dir ? lBefore : iBefore;
        if (sw) { sk[i] = kb2; sk[l] = ka; sp[i] = ib; sp[l] = ia; }
      }
      __syncthreads();
    }
  }
  if (tid <= 120) {
    if (sk[tid] - sk[tid + 1] < DELTA) {
      int p = atomicAdd(mcnt, 2);
      if (p + 1 < MAXMARK) {
        marks[p]     = m * KK + sp[tid];
        marks[p + 1] = m * KK + sp[tid + 1];
      }
    }
  }
}

// ------- Kernel E3: exact f64 rescore of marked candidates (in-place into z64) -------
__global__ __launch_bounds__(256) void k_rescore(
    const float* __restrict__ kb, const int* __restrict__ cidx,
    const double* __restrict__ mp64, const float* __restrict__ Ws1,
    const float* __restrict__ bs1, const float* __restrict__ Ws2,
    const float* __restrict__ bs2, const int* __restrict__ marks,
    const int* __restrict__ mcnt, double* __restrict__ z64) {
  int cnt = *mcnt; if (cnt > MAXMARK) cnt = MAXMARK;
  __shared__ float sc[DD];
  __shared__ double sred[256];
  int tid = threadIdx.x;
  for (int it = blockIdx.x; it < cnt; it += gridDim.x) {
    int r = marks[it];
    int m = r / KK;
    int row = cidx[r];
    for (int d = tid; d < DD; d += 256) sc[d] = kb[(size_t)row * DD + d];
    __syncthreads();
    double pz = 0.0;
    for (int e = tid; e < DD; e += 256) {
      double a = 0.0;
      for (int d = 0; d < DD; ++d) a += (double)sc[d] * (double)Ws1[(size_t)(DD + d) * DD + e];
      double hv = mp64[(size_t)m * DD + e] + a + (double)bs1[e];
      if (hv > 0) pz += hv * (double)Ws2[e];
    }
    sred[tid] = pz; __syncthreads();
    for (int s = 128; s > 0; s >>= 1) { if (tid < s) sred[tid] += sred[tid + s]; __syncthreads(); }
    if (tid == 0) z64[r] = sred[0] + (double)bs2[0];
    __syncthreads();
  }
}

// ---------------- Kernel F: per-mention top-100 of 200 (bitonic 256) ----------------
__global__ __launch_bounds__(256) void k_final(
    const double* __restrict__ z64, const int* __restrict__ cidx, float* __restrict__ out) {
  int m = blockIdx.x;
  __shared__ double sk[256];
  __shared__ int sp[256];
  int tid = threadIdx.x;
  if (tid < KK) { sk[tid] = z64[(size_t)m * KK + tid]; sp[tid] = tid; }
  else { sk[tid] = -INFINITY; sp[tid] = 0x7fffffff; }
  __syncthreads();
  for (int k = 2; k <= 256; k <<= 1) {
    for (int j = k >> 1; j > 0; j >>= 1) {
      int i = tid, l = i ^ j;
      if (l > i) {
        double ka = sk[i], kb2 = sk[l];
        int ia = sp[i], ib = sp[l];
        bool lBefore = (kb2 > ka) || (kb2 == ka && ib < ia);
        bool iBefore = (ka > kb2) || (ka == kb2 && ia < ib);
        bool dir = ((i & k) == 0);
        bool sw = dir ? lBefore : iBefore;
        if (sw) { sk[i] = kb2; sk[l] = ka; sp[i] = ib; sp[l] = ia; }
      }
      __syncthreads();
    }
  }
  if (tid < TOPK) {
    double z = sk[tid];
    out[(size_t)m * TOPK + tid] = (float)(1.0 / (1.0 + exp(-z)));
    out[(size_t)MM * TOPK + (size_t)m * TOPK + tid] = (float)cidx[(size_t)m * KK + sp[tid]];
  }
}

// ---------------- host ----------------
extern "C" void kernel_launch(void* const* d_in, const int* in_sizes, int n_in,
                              void* d_out, int out_size, void* d_ws, size_t ws_size,
                              hipStream_t stream) {
  const float* text  = (const float*)d_in[0];
  const float* kb    = (const float*)d_in[1];
  const float* Wret  = (const float*)d_in[2];
  const float* bret  = (const float*)d_in[3];
  const float* Ws1   = (const float*)d_in[4];
  const float* bs1   = (const float*)d_in[5];
  const float* Ws2   = (const float*)d_in[6];
  const float* bs2   = (const float*)d_in[7];
  const int* msent   = (const int*)d_in[8];
  const int* mstart  = (const int*)d_in[9];
  const int* mlen    = (const int*)d_in[10];
  float* out = (float*)d_out;

  char* ws = (char*)d_ws;
  size_t off = 0;
  auto alloc = [&](size_t bytes) -> void* {
    void* p = ws + off;
    off = (off + bytes + 255) & ~(size_t)255;
    return p;
  };
  double* me64 = (double*)alloc((size_t)MM * DD * 8);
  double* q64  = (double*)alloc((size_t)MM * DD * 8);
  unsigned short* qb16 = (unsigned short*)alloc((size_t)MM * DD * 2);
  float*  tthr = (float*) alloc((size_t)MM * 4);
  double* mp64 = (double*)alloc((size_t)MM * DD * 8);
  float*  mp32 = (float*) alloc((size_t)MM * DD * 4);
  int*    cidx = (int*)   alloc((size_t)MM * KK * 4);
  double* z64  = (double*)alloc((size_t)MM * KK * 8);
  int*    marks = (int*)  alloc((size_t)MAXMARK * 4);
  int*    mcnt  = (int*)  alloc(256);
  int*    gcnt  = (int*)  alloc((size_t)MM * 4);
  uint2*  gcand = (uint2*)alloc((size_t)MM * SURV_CAP * 8);
  unsigned short* Bth = (unsigned short*)alloc((size_t)DD * DD * 2);
  unsigned short* Btl = (unsigned short*)alloc((size_t)DD * DD * 2);
  (void)ws_size;

  k_mention_emb<<<MM, 256, 0, stream>>>(text, msent, mstart, mlen, me64);
  k_query<<<MM, 256, 0, stream>>>(me64, Wret, bret, q64, qb16, tthr);
  k_mpart<<<MM, 256, 0, stream>>>(me64, Ws1, mp64, mp32);
  k_prep<<<DD, 256, 0, stream>>>(Ws1, Bth, Btl);

  hipMemsetAsync(gcnt, 0, (size_t)MM * 4, stream);
  k_sims_mfma<<<NKB / 64, 256, 0, stream>>>(qb16, kb, tthr, gcnt, gcand);
  k_select<<<MM, 256, 0, stream>>>(gcand, gcnt, kb, q64, cidx);

  k_score_mfma<<<(MM * KK) / 64, 256, 0, stream>>>(kb, cidx, mp32, Bth, Btl, bs1, Ws2, bs2, z64);
  hipMemsetAsync(mcnt, 0, 4, stream);
  k_mark<<<MM, 256, 0, stream>>>(z64, marks, mcnt);
  k_rescore<<<2048, 256, 0, stream>>>(kb, cidx, mp64, Ws1, bs1, Ws2, bs2, marks, mcnt, z64);
  k_final<<<MM, 256, 0, stream>>>(z64, cidx, out);
}